// Round 16
// baseline (382.760 us; speedup 1.0000x reference)
//
#include <hip/hip_runtime.h>
#include <hip/hip_bf16.h>
#include <math.h>

#define FDIM 15
#define FPAD 16
#define NEG_SLOPE 0.2f
// dst-buckets of 256 nodes each: bucket = dst >> 8, local = dst & 255
#define BSH 8
#define BWID 256
// R5/R9 lesson: per-(block,bucket) chunk contiguity rules. 256 blocks ->
// ~33 edges (132B) per chunk. 1024 thr/block supplies occupancy.
#define HB_GRID 256
#define HB_BLK 1024

typedef _Float16 half_t;

__device__ __forceinline__ float leaky(float e) {
  return fmaxf(NEG_SLOPE * e, e);   // valid for slope<1
}

__global__ void k_zero(int* __restrict__ p, int n) {
  int i = blockIdx.x * blockDim.x + threadIdx.x;
  if (i < n) p[i] = 0;
}

// ---- generic annotation-MLP stage rider (K=300 fixed, Nout<=300) ----
// Runs as the first mlpG blocks of a host kernel (R14/R15 lesson: the MLP is
// latency-bound; hide it under kernels with idle capacity).
__device__ __forceinline__ void mlp_rider(int g, int tid, int nthreads,
                                          const float* __restrict__ mIn,
                                          const float* __restrict__ mW,
                                          const float* __restrict__ mB,
                                          float* __restrict__ mOut,
                                          int Nout, int mAct,
                                          float* mins) {
  for (int k = tid; k < 300; k += nthreads) mins[k] = mIn[(size_t)g * 300 + k];
  __syncthreads();
  int j1 = tid;
  int j2 = tid + nthreads;
  bool p1 = (j1 < Nout), p2 = (j2 < Nout);
  float a0 = 0.f, a1 = 0.f, a2 = 0.f, a3 = 0.f;
  float b0 = 0.f, b1 = 0.f, b2 = 0.f, b3 = 0.f;
  if (p1) {
    for (int k = 0; k < 300; k += 4) {
      float i0 = mins[k], i1 = mins[k + 1], i2 = mins[k + 2], i3 = mins[k + 3];
      float w0 = mW[k * Nout + j1];
      float w1 = mW[(k + 1) * Nout + j1];
      float w2 = mW[(k + 2) * Nout + j1];
      float w3 = mW[(k + 3) * Nout + j1];
      a0 += i0 * w0; a1 += i1 * w1; a2 += i2 * w2; a3 += i3 * w3;
      if (p2) {
        float v0 = mW[k * Nout + j2];
        float v1 = mW[(k + 1) * Nout + j2];
        float v2 = mW[(k + 2) * Nout + j2];
        float v3 = mW[(k + 3) * Nout + j2];
        b0 += i0 * v0; b1 += i1 * v1; b2 += i2 * v2; b3 += i3 * v3;
      }
    }
    float r1 = mB[j1] + (a0 + a1) + (a2 + a3);
    if (mAct == 1) r1 = fmaxf(r1, 0.f);
    else if (mAct == 2) r1 = 1.f / (1.f + expf(-r1));
    mOut[(size_t)g * Nout + j1] = r1;
    if (p2) {
      float r2 = mB[j2] + (b0 + b1) + (b2 + b3);
      if (mAct == 1) r2 = fmaxf(r2, 0.f);
      else if (mAct == 2) r2 = 1.f / (1.f + expf(-r2));
      mOut[(size_t)g * Nout + j2] = r2;
    }
  }
}

// ---- bucket histogram + per-block hist spill (+ MLP s1 rider) ----
__global__ void k_bhist2(const int* __restrict__ dstI, int* __restrict__ bcnt,
                         int* __restrict__ hists,
                         int n_tot, int n_real, int NB,
                         const float* __restrict__ mIn, const float* __restrict__ mW,
                         const float* __restrict__ mB, float* __restrict__ mOut,
                         int mNout, int mAct, int mlpG) {
  __shared__ int hist[512];
  __shared__ float mins[304];
  int tid = threadIdx.x;
  if ((int)blockIdx.x < mlpG) {
    mlp_rider(blockIdx.x, tid, blockDim.x, mIn, mW, mB, mOut, mNout, mAct, mins);
    return;
  }
  int bid = blockIdx.x - mlpG;
  for (int i = tid; i < NB; i += blockDim.x) hist[i] = 0;
  __syncthreads();
  int stride = HB_GRID * blockDim.x;
  for (int i = bid * blockDim.x + tid; i < n_tot; i += stride) {
    int d = (i < n_real) ? dstI[i] : (i - n_real);
    atomicAdd(&hist[d >> BSH], 1);
  }
  __syncthreads();
  for (int i = tid; i < NB; i += blockDim.x) {
    int h = hist[i];
    hists[bid * 512 + i] = h;
    if (h) atomicAdd(&bcnt[i], h);
  }
}

// ---- exclusive scan of bucket counts (single block, 512 thr) ----
__global__ void k_bscan(const int* __restrict__ bcnt, int* __restrict__ boff,
                        int* __restrict__ rowptr,
                        int NB, int N, int total) {
  __shared__ int s[512];
  int tid = threadIdx.x;
  int v = (tid < NB) ? bcnt[tid] : 0;
  s[tid] = v;
  __syncthreads();
  for (int off = 1; off < 512; off <<= 1) {
    int add = (tid >= off) ? s[tid - off] : 0;
    __syncthreads();
    s[tid] += add;
    __syncthreads();
  }
  if (tid < NB) boff[tid] = s[tid] - v;
  if (tid == NB - 1) boff[NB] = s[tid];
  if (tid == 0) rowptr[N] = total;
}

// ---- per-(block,bucket) base offsets: column scan of hists + boff ----
__global__ void k_base(const int* __restrict__ hists, const int* __restrict__ boff,
                       int* __restrict__ base, int nblk) {
  __shared__ int s[256];
  int b = blockIdx.x;     // bucket
  int tid = threadIdx.x;  // block index
  int v = (tid < nblk) ? hists[tid * 512 + b] : 0;
  s[tid] = v;
  __syncthreads();
  for (int off = 1; off < 256; off <<= 1) {
    int add = (tid >= off) ? s[tid - off] : 0;
    __syncthreads();
    s[tid] += add;
    __syncthreads();
  }
  if (tid < nblk) base[tid * 512 + b] = boff[b] + s[tid] - v;
}

// ---- single-pass partition using precomputed bases (+ MLP s2 rider) ----
__global__ void k_bpart2(const int* __restrict__ srcI, const int* __restrict__ dstI,
                         const int* __restrict__ base, int* __restrict__ bbuf,
                         int n_tot, int n_real, int NB,
                         const float* __restrict__ mIn, const float* __restrict__ mW,
                         const float* __restrict__ mB, float* __restrict__ mOut,
                         int mNout, int mAct, int mlpG) {
  __shared__ int cur[512];
  __shared__ float mins[304];
  int tid = threadIdx.x;
  if ((int)blockIdx.x < mlpG) {
    mlp_rider(blockIdx.x, tid, blockDim.x, mIn, mW, mB, mOut, mNout, mAct, mins);
    return;
  }
  int bid = blockIdx.x - mlpG;
  for (int i = tid; i < NB; i += blockDim.x) cur[i] = base[bid * 512 + i];
  __syncthreads();
  int stride = HB_GRID * blockDim.x;
  for (int i = bid * blockDim.x + tid; i < n_tot; i += stride) {
    int s, d;
    if (i < n_real) { s = srcI[i]; d = dstI[i]; }
    else { s = d = i - n_real; }
    int b = d >> BSH;
    int p = atomicAdd(&cur[b], 1);
    bbuf[p] = (s << BSH) | (d & (BWID - 1));
  }
}

// ---- per-bucket: per-dst hist -> scan -> rowptr + csr scatter (512 thr) ----
// csr stores PRE-SCALED byte offsets (src*32) for k_gat's hp gathers.
__global__ void k_bbuild(const int* __restrict__ boff, const int* __restrict__ bbuf,
                         int* __restrict__ rowptr, int* __restrict__ csr, int N) {
  __shared__ int hist[BWID];
  __shared__ int sc[BWID];
  int b = blockIdx.x;
  int tid = threadIdx.x;  // 512
  int base_dst = b << BSH;
  int nd = min(BWID, N - base_dst);
  int s0 = boff[b], s1 = boff[b + 1];
  if (tid < BWID) hist[tid] = 0;
  __syncthreads();
  for (int j = s0 + tid; j < s1; j += 512)
    atomicAdd(&hist[bbuf[j] & (BWID - 1)], 1);
  __syncthreads();
  int v = 0;
  if (tid < BWID) { v = hist[tid]; sc[tid] = v; }
  __syncthreads();
  for (int off = 1; off < BWID; off <<= 1) {
    int add = 0;
    if (tid < BWID && tid >= off) add = sc[tid - off];
    __syncthreads();
    if (tid < BWID) sc[tid] += add;
    __syncthreads();
  }
  if (tid < nd) rowptr[base_dst + tid] = s0 + sc[tid] - v;
  __syncthreads();
  if (tid < BWID) hist[tid] = sc[tid] - v;
  __syncthreads();
  for (int j = s0 + tid; j < s1; j += 512) {
    int e = bbuf[j];
    int dl = e & (BWID - 1);
    int p = s0 + atomicAdd(&hist[dl], 1);
    csr[p] = (e >> BSH) << 5;   // src * 32 bytes
  }
}

// ---- h = in @ W (fp16, as packed in slot 15) ; ad_ fp32 (layer 0 only) ----
__global__ void k_transform(const float* __restrict__ in, int ld_in,
                            const float* __restrict__ W,
                            const float* __restrict__ a_s,
                            const float* __restrict__ a_d,
                            half_t* __restrict__ hp,
                            float* __restrict__ ad_,
                            int n_nodes) {
  __shared__ float Ws[FDIM * FDIM];
  __shared__ float asv[FDIM], adv[FDIM];
  int tid = threadIdx.x;
  if (tid < FDIM * FDIM) Ws[tid] = W[tid];
  if (tid < FDIM) { asv[tid] = a_s[tid]; adv[tid] = a_d[tid]; }
  __syncthreads();
  int n = blockIdx.x * blockDim.x + tid;
  if (n >= n_nodes) return;
  float xin[FDIM];
#pragma unroll
  for (int j = 0; j < FDIM; ++j) xin[j] = in[n * ld_in + j];
  float sa = 0.f, da = 0.f;
  half_t hrow[FPAD];
#pragma unroll
  for (int o = 0; o < FDIM; ++o) {
    float acc = 0.f;
#pragma unroll
    for (int k = 0; k < FDIM; ++k) acc += xin[k] * Ws[k * FDIM + o];
    hrow[o] = (half_t)acc;
    sa += acc * asv[o];
    da += acc * adv[o];
  }
  hrow[FDIM] = (half_t)sa;
  ad_[n] = da;
  float4 w0, w1;
  __builtin_memcpy(&w0, &hrow[0], 16);
  __builtin_memcpy(&w1, &hrow[8], 16);
  float4* dst = (float4*)(hp + (size_t)n * FPAD);
  dst[0] = w0;
  dst[1] = w1;
}

// ---- fused GAT aggregate + FFN (+ next-layer transform) + MLP rider ----
// R8 main loop (best measured, 3x confirmed local optimum).
__global__ void k_gat(const int* __restrict__ rowptr, const int* __restrict__ csrB,
                      const half_t* __restrict__ hp, const float* __restrict__ ad_,
                      const float* __restrict__ cb, const float* __restrict__ fW,
                      const float* __restrict__ fb,
                      const float* __restrict__ nW, const float* __restrict__ nas,
                      const float* __restrict__ nad,
                      half_t* __restrict__ hp2, float* __restrict__ ad2,
                      float* __restrict__ fout,
                      const float* __restrict__ mIn, const float* __restrict__ mW,
                      const float* __restrict__ mB, float* __restrict__ mOut,
                      int mNout, int mAct, int mlpG,
                      int n_nodes, int do_relu, int fuse) {
  __shared__ float Ws[FDIM * FDIM];
  __shared__ float W2s[FDIM * FDIM];
  __shared__ float cbv[FDIM], fbv[FDIM], as2v[FDIM], ad2v[FDIM];
  __shared__ float aggT[16][16];
  __shared__ float outT[16][16];
  __shared__ float mins[304];
  int tid = threadIdx.x;

  if ((int)blockIdx.x < mlpG) {
    mlp_rider(blockIdx.x, tid, blockDim.x, mIn, mW, mB, mOut, mNout, mAct, mins);
    return;
  }

  if (tid < FDIM * FDIM) Ws[tid] = fW[tid];
  if (tid < FDIM) { cbv[tid] = cb[tid]; fbv[tid] = fb[tid]; }
  if (fuse) {
    if (tid < FDIM * FDIM) W2s[tid] = nW[tid];
    if (tid < FDIM) { as2v[tid] = nas[tid]; ad2v[tid] = nad[tid]; }
  }
  __syncthreads();
  int dl = tid >> 4;          // local dst 0..15
  int f  = tid & 15;          // feature lane 0..15 (slot 15 carries `as`)
  int d  = ((int)blockIdx.x - mlpG) * 16 + dl;
  float val = 0.f;
  if (d < n_nodes) {
    int rs = rowptr[d], re = rowptr[d + 1];
    float adv = ad_[d];
    const char* hb = (const char*)hp;
    int fo = f << 1;
    float den0 = 0.f, acc0 = 0.f, den1 = 0.f, acc1 = 0.f;
    int j = rs;
    for (; j + 7 < re; j += 8) {
      int o0 = csrB[j],     o1 = csrB[j + 1], o2 = csrB[j + 2], o3 = csrB[j + 3];
      int o4 = csrB[j + 4], o5 = csrB[j + 5], o6 = csrB[j + 6], o7 = csrB[j + 7];
      float hv0 = (float)*(const half_t*)(hb + o0 + fo);
      float hv1 = (float)*(const half_t*)(hb + o1 + fo);
      float hv2 = (float)*(const half_t*)(hb + o2 + fo);
      float hv3 = (float)*(const half_t*)(hb + o3 + fo);
      float hv4 = (float)*(const half_t*)(hb + o4 + fo);
      float hv5 = (float)*(const half_t*)(hb + o5 + fo);
      float hv6 = (float)*(const half_t*)(hb + o6 + fo);
      float hv7 = (float)*(const half_t*)(hb + o7 + fo);
      float w0 = __expf(leaky(__shfl(hv0, 15, 16) + adv));
      float w1 = __expf(leaky(__shfl(hv1, 15, 16) + adv));
      float w2 = __expf(leaky(__shfl(hv2, 15, 16) + adv));
      float w3 = __expf(leaky(__shfl(hv3, 15, 16) + adv));
      float w4 = __expf(leaky(__shfl(hv4, 15, 16) + adv));
      float w5 = __expf(leaky(__shfl(hv5, 15, 16) + adv));
      float w6 = __expf(leaky(__shfl(hv6, 15, 16) + adv));
      float w7 = __expf(leaky(__shfl(hv7, 15, 16) + adv));
      den0 += w0; acc0 += hv0 * w0;
      den1 += w1; acc1 += hv1 * w1;
      den0 += w2; acc0 += hv2 * w2;
      den1 += w3; acc1 += hv3 * w3;
      den0 += w4; acc0 += hv4 * w4;
      den1 += w5; acc1 += hv5 * w5;
      den0 += w6; acc0 += hv6 * w6;
      den1 += w7; acc1 += hv7 * w7;
    }
    for (; j < re; ++j) {
      int o0 = csrB[j];
      float hv0 = (float)*(const half_t*)(hb + o0 + fo);
      float w0 = __expf(leaky(__shfl(hv0, 15, 16) + adv));
      den0 += w0; acc0 += hv0 * w0;
    }
    val = (acc0 + acc1) / (den0 + den1 + 1e-16f);
  }
  aggT[dl][f] = (f < FDIM) ? (val + cbv[f]) : 0.f;
  __syncthreads();
  int o = f;
  float ffn = 0.f;
  if (o < FDIM) {
    ffn = fbv[o];
#pragma unroll
    for (int k = 0; k < FDIM; ++k) ffn += aggT[dl][k] * Ws[k * FDIM + o];
    if (do_relu) ffn = fmaxf(ffn, 0.f);
  }
  if (!fuse) {
    if (d < n_nodes) fout[d * FPAD + o] = (o < FDIM) ? ffn : 0.f;
    return;
  }
  // ---- fused next-layer transform: h2 = out @ nW ; sa2/da2 reductions ----
  outT[dl][o] = ffn;   // o==15 lane wrote ffn=0
  __syncthreads();
  if (d < n_nodes) {
    float h2 = 0.f;
    if (o < FDIM) {
#pragma unroll
      for (int k = 0; k < FDIM; ++k) h2 += outT[dl][k] * W2s[k * FDIM + o];
    }
    float pa = (o < FDIM) ? h2 * as2v[o] : 0.f;
    float pd = (o < FDIM) ? h2 * ad2v[o] : 0.f;
#pragma unroll
    for (int k = 8; k; k >>= 1) {
      pa += __shfl_xor(pa, k, 16);
      pd += __shfl_xor(pd, k, 16);
    }
    hp2[(size_t)d * FPAD + o] = (half_t)((o < FDIM) ? h2 : pa);
    if (o == 0) ad2[d] = pd;
  }
}

// ---- pooling: one block per graph (batch sorted), no atomics ----
__device__ __forceinline__ int lowerb(const int* __restrict__ a, int n, int key) {
  int lo = 0, hi = n;
  while (lo < hi) { int mid = (lo + hi) >> 1; if (a[mid] < key) lo = mid + 1; else hi = mid; }
  return lo;
}

__global__ void k_pool(const float* __restrict__ fout, const int* __restrict__ batch,
                       float* __restrict__ pooled, int n_nodes) {
  __shared__ float ss[256], sm[256];
  int g = blockIdx.x;
  int tid = threadIdx.x;
  int s = lowerb(batch, n_nodes, g);
  int e = lowerb(batch, n_nodes, g + 1);
  int f = tid & 15;
  float sum = 0.f, mx = -INFINITY;
  for (int n = s + (tid >> 4); n < e; n += 16) {
    float v = fout[n * FPAD + f];
    sum += v;
    mx = fmaxf(mx, v);
  }
  ss[tid] = sum; sm[tid] = mx;
  __syncthreads();
  for (int step = 128; step >= 16; step >>= 1) {
    if (tid < step) { ss[tid] += ss[tid + step]; sm[tid] = fmaxf(sm[tid], sm[tid + step]); }
    __syncthreads();
  }
  if (tid < FDIM) {
    float cnt = (float)(e - s);
    float sv = ss[tid];
    pooled[g * 45 + tid] = sv;
    pooled[g * 45 + 15 + tid] = sm[tid];
    pooled[g * 45 + 30 + tid] = sv / fmaxf(cnt, 1.f);
  }
}

// ---- head: z=[pooled,xann] -> relu(z@m1W+m1b) -> sigmoid(@m2W+m2b) ----
__global__ void k_final(const float* __restrict__ pooled, const float* __restrict__ xann,
                        const float* __restrict__ m1W, const float* __restrict__ m1b,
                        const float* __restrict__ m2W, const float* __restrict__ m2b,
                        float* __restrict__ out) {
  __shared__ float z[90];
  __shared__ float z2[90];
  __shared__ float ps[128];
  int g = blockIdx.x;
  int t = threadIdx.x;  // 128
  if (t < 45) z[t] = pooled[g * 45 + t];
  else if (t < 90) z[t] = xann[g * 45 + (t - 45)];
  __syncthreads();
  if (t < 90) {
    float a0 = 0.f, a1 = 0.f;
    for (int k = 0; k < 90; k += 2) {
      float w0 = m1W[k * 90 + t];
      float w1 = m1W[(k + 1) * 90 + t];
      a0 += z[k] * w0; a1 += z[k + 1] * w1;
    }
    z2[t] = fmaxf(m1b[t] + a0 + a1, 0.f);
  }
  __syncthreads();
  if (t < 90) ps[t] = z2[t] * m2W[t];
  else ps[t] = 0.f;
  __syncthreads();
  if (t < 64) {
    float v = ps[t] + ps[t + 64];
#pragma unroll
    for (int k2 = 32; k2; k2 >>= 1) v += __shfl_xor(v, k2, 64);
    if (t == 0) out[g] = 1.f / (1.f + expf(-(v + m2b[0])));
  }
}

extern "C" void kernel_launch(void* const* d_in, const int* in_sizes, int n_in,
                              void* d_out, int out_size, void* d_ws, size_t ws_size,
                              hipStream_t stream) {
  const float* x   = (const float*)d_in[0];
  const int* ei    = (const int*)d_in[1];
  const int* batch = (const int*)d_in[2];
  const float* xA  = (const float*)d_in[3];

  const int N = in_sizes[0] / FDIM;
  const int E = in_sizes[1] / 2;
  const int G = in_sizes[3] / 300;
  const int ET = E + N;
  const int NB = (N + BWID - 1) >> BSH;   // dst buckets (<=512 for N<=131072)

  const int* srcI = ei;
  const int* dstI = ei + E;

  // ---- workspace layout (4-byte words) ----
  float* ws = (float*)d_ws;
  size_t layerW = (size_t)34 * N;  // hpA(8N)+hpB(8N)+adA(N)+adB(N)+fout(16N)
  size_t uSize = layerW > (size_t)ET ? layerW : (size_t)ET;
  size_t off = 0;
  int*    bbuf = (int*)(ws + off);
  half_t* hpA  = (half_t*)(ws + off);
  half_t* hpB  = (half_t*)(ws + off + (size_t)8 * N);
  float*  adA  = ws + off + (size_t)16 * N;
  float*  adB  = ws + off + (size_t)17 * N;
  float*  fout = ws + off + (size_t)18 * N;
  off += uSize;
  int*   rowptr = (int*)(ws + off); off += N + 1;
  int*   csr    = (int*)(ws + off); off += (size_t)ET;
  int*   bcnt   = (int*)(ws + off); off += 516;
  int*   boff   = (int*)(ws + off); off += 516;
  int*   hists  = (int*)(ws + off); off += 256 * 512;
  int*   base   = (int*)(ws + off); off += 256 * 512;
  float* pooled = ws + off; off += (size_t)G * 45;
  float* a1     = ws + off; off += (size_t)G * 300;
  float* a2     = ws + off; off += (size_t)G * 300;
  float* xann   = ws + off; off += (size_t)G * 45;

  const int B = 256;
  const int gN = (N + B - 1) / B;

  // ---- weights ----
  const float* cW1  = (const float*)d_in[4];
  const float* cas1 = (const float*)d_in[5];
  const float* cad1 = (const float*)d_in[6];
  const float* cb1  = (const float*)d_in[7];
  const float* fW1  = (const float*)d_in[8];
  const float* fb1  = (const float*)d_in[9];
  const float* cW2  = (const float*)d_in[10];
  const float* cas2 = (const float*)d_in[11];
  const float* cad2 = (const float*)d_in[12];
  const float* cb2  = (const float*)d_in[13];
  const float* fW2  = (const float*)d_in[14];
  const float* fb2  = (const float*)d_in[15];
  const float* cW3  = (const float*)d_in[16];
  const float* cas3 = (const float*)d_in[17];
  const float* cad3 = (const float*)d_in[18];
  const float* cb3  = (const float*)d_in[19];
  const float* fW3  = (const float*)d_in[20];
  const float* fb3  = (const float*)d_in[21];
  const float* m1W  = (const float*)d_in[22];
  const float* m1b  = (const float*)d_in[23];
  const float* aW1  = (const float*)d_in[24];
  const float* ab1  = (const float*)d_in[25];
  const float* aW2  = (const float*)d_in[26];
  const float* ab2  = (const float*)d_in[27];
  const float* aW3  = (const float*)d_in[28];
  const float* ab3  = (const float*)d_in[29];
  const float* aW4  = (const float*)d_in[30];
  const float* ab4  = (const float*)d_in[31];
  const float* m2W  = (const float*)d_in[32];
  const float* m2b  = (const float*)d_in[33];

  // ---- bucketed CSR build (s1 rides bhist, s2 rides bpart) ----
  k_zero<<<(NB + B - 1) / B, B, 0, stream>>>(bcnt, NB);
  k_bhist2<<<HB_GRID + G, HB_BLK, 0, stream>>>(dstI, bcnt, hists, ET, E, NB,
                                               xA, aW1, ab1, a1, 300, 1, G);
  k_bscan<<<1, 512, 0, stream>>>(bcnt, boff, rowptr, NB, N, ET);
  k_base<<<NB, 256, 0, stream>>>(hists, boff, base, HB_GRID);
  k_bpart2<<<HB_GRID + G, HB_BLK, 0, stream>>>(srcI, dstI, base, bbuf, ET, E, NB,
                                               a1, aW2, ab2, a2, 300, 1, G);
  k_bbuild<<<NB, 512, 0, stream>>>(boff, bbuf, rowptr, csr, N);

  // ---- 3 GAT layers (s3 on gat1, s4 on gat2, gat3 bare) ----
  const int gGat = (N + 15) / 16;
  k_transform<<<gN, B, 0, stream>>>(x, FDIM, cW1, cas1, cad1, hpA, adA, N);
  k_gat<<<gGat + G, B, 0, stream>>>(rowptr, csr, hpA, adA, cb1, fW1, fb1,
                                    cW2, cas2, cad2, hpB, adB, nullptr,
                                    a2, aW3, ab3, a1, 300, 2, G,
                                    N, 1, 1);
  k_gat<<<gGat + G, B, 0, stream>>>(rowptr, csr, hpB, adB, cb2, fW2, fb2,
                                    cW3, cas3, cad3, hpA, adA, nullptr,
                                    a1, aW4, ab4, xann, 45, 0, G,
                                    N, 1, 1);
  k_gat<<<gGat, B, 0, stream>>>(rowptr, csr, hpA, adA, cb3, fW3, fb3,
                                nullptr, nullptr, nullptr, nullptr, nullptr, fout,
                                nullptr, nullptr, nullptr, nullptr, 0, 0, 0,
                                N, 0, 0);

  // ---- pooling (pure) ----
  k_pool<<<G, B, 0, stream>>>(fout, batch, pooled, N);

  // ---- head ----
  k_final<<<G, 128, 0, stream>>>(pooled, xann, m1W, m1b, m2W, m2b, (float*)d_out);
}

// Round 17
// 356.292 us; speedup vs baseline: 1.0743x; 1.0743x over previous
//
#include <hip/hip_runtime.h>
#include <hip/hip_bf16.h>
#include <math.h>

#define FDIM 15
#define FPAD 16
#define NEG_SLOPE 0.2f
// dst-buckets of 256 nodes each: bucket = dst >> 8, local = dst & 255
#define BSH 8
#define BWID 256
// R5/R9 lesson: per-(block,bucket) chunk contiguity rules. 256 blocks ->
// ~33 edges (132B) per chunk. 1024 thr/block supplies occupancy.
#define HB_GRID 256
#define HB_BLK 1024

typedef _Float16 half_t;

__device__ __forceinline__ float leaky(float e) {
  return fmaxf(NEG_SLOPE * e, e);   // valid for slope<1
}

__global__ void k_zero(int* __restrict__ p, int n) {
  int i = blockIdx.x * blockDim.x + threadIdx.x;
  if (i < n) p[i] = 0;
}

// ---- bucket histogram over all edges (incl. self loops) ----
__global__ void k_bhist(const int* __restrict__ dstI, int* __restrict__ bcnt,
                        int n_tot, int n_real, int NB) {
  __shared__ int hist[512];
  int tid = threadIdx.x;
  for (int i = tid; i < NB; i += blockDim.x) hist[i] = 0;
  __syncthreads();
  int stride = gridDim.x * blockDim.x;
  for (int i = blockIdx.x * blockDim.x + tid; i < n_tot; i += stride) {
    int d = (i < n_real) ? dstI[i] : (i - n_real);
    atomicAdd(&hist[d >> BSH], 1);
  }
  __syncthreads();
  for (int i = tid; i < NB; i += blockDim.x)
    if (hist[i]) atomicAdd(&bcnt[i], hist[i]);
}

// ---- exclusive scan of bucket counts (single block, 512 thr) ----
__global__ void k_bscan(const int* __restrict__ bcnt, int* __restrict__ boff,
                        int* __restrict__ bcur, int* __restrict__ rowptr,
                        int NB, int N, int total) {
  __shared__ int s[512];
  int tid = threadIdx.x;
  int v = (tid < NB) ? bcnt[tid] : 0;
  s[tid] = v;
  __syncthreads();
  for (int off = 1; off < 512; off <<= 1) {
    int add = (tid >= off) ? s[tid - off] : 0;
    __syncthreads();
    s[tid] += add;
    __syncthreads();
  }
  if (tid < NB) { int e = s[tid] - v; boff[tid] = e; bcur[tid] = e; }
  if (tid == NB - 1) boff[NB] = s[tid];
  if (tid == 0) rowptr[N] = total;
}

// ---- partition edges into dst-buckets, packed (src<<8 | dst&255) ----
__global__ void k_bpart(const int* __restrict__ srcI, const int* __restrict__ dstI,
                        int* __restrict__ bcur, int* __restrict__ bbuf,
                        int n_tot, int n_real, int NB) {
  __shared__ int hist[512];
  __shared__ int base[512];
  int tid = threadIdx.x;
  for (int i = tid; i < NB; i += blockDim.x) hist[i] = 0;
  __syncthreads();
  int stride = gridDim.x * blockDim.x;
  int g0 = blockIdx.x * blockDim.x + tid;
  for (int i = g0; i < n_tot; i += stride) {
    int d = (i < n_real) ? dstI[i] : (i - n_real);
    atomicAdd(&hist[d >> BSH], 1);
  }
  __syncthreads();
  for (int i = tid; i < NB; i += blockDim.x)
    base[i] = hist[i] ? atomicAdd(&bcur[i], hist[i]) : 0;
  __syncthreads();
  for (int i = tid; i < NB; i += blockDim.x) hist[i] = 0;
  __syncthreads();
  for (int i = g0; i < n_tot; i += stride) {
    int s, d;
    if (i < n_real) { s = srcI[i]; d = dstI[i]; }
    else { s = d = i - n_real; }
    int b = d >> BSH;
    int p = base[b] + atomicAdd(&hist[b], 1);
    bbuf[p] = (s << BSH) | (d & (BWID - 1));
  }
}

// ---- per-bucket: per-dst hist -> scan -> rowptr + csr scatter (512 thr) ----
// csr stores PRE-SCALED byte offsets (src*32) for k_gat's hp gathers.
__global__ void k_bbuild(const int* __restrict__ boff, const int* __restrict__ bbuf,
                         int* __restrict__ rowptr, int* __restrict__ csr, int N) {
  __shared__ int hist[BWID];
  __shared__ int sc[BWID];
  int b = blockIdx.x;
  int tid = threadIdx.x;  // 512
  int base_dst = b << BSH;
  int nd = min(BWID, N - base_dst);
  int s0 = boff[b], s1 = boff[b + 1];
  if (tid < BWID) hist[tid] = 0;
  __syncthreads();
  for (int j = s0 + tid; j < s1; j += 512)
    atomicAdd(&hist[bbuf[j] & (BWID - 1)], 1);
  __syncthreads();
  int v = 0;
  if (tid < BWID) { v = hist[tid]; sc[tid] = v; }
  __syncthreads();
  for (int off = 1; off < BWID; off <<= 1) {
    int add = 0;
    if (tid < BWID && tid >= off) add = sc[tid - off];
    __syncthreads();
    if (tid < BWID) sc[tid] += add;
    __syncthreads();
  }
  if (tid < nd) rowptr[base_dst + tid] = s0 + sc[tid] - v;
  __syncthreads();
  if (tid < BWID) hist[tid] = sc[tid] - v;
  __syncthreads();
  for (int j = s0 + tid; j < s1; j += 512) {
    int e = bbuf[j];
    int dl = e & (BWID - 1);
    int p = s0 + atomicAdd(&hist[dl], 1);
    csr[p] = (e >> BSH) << 5;   // src * 32 bytes
  }
}

// ---- h = in @ W (fp16, as packed in slot 15) ; ad_ fp32 (layer 0 only) ----
__global__ void k_transform(const float* __restrict__ in, int ld_in,
                            const float* __restrict__ W,
                            const float* __restrict__ a_s,
                            const float* __restrict__ a_d,
                            half_t* __restrict__ hp,
                            float* __restrict__ ad_,
                            int n_nodes) {
  __shared__ float Ws[FDIM * FDIM];
  __shared__ float asv[FDIM], adv[FDIM];
  int tid = threadIdx.x;
  if (tid < FDIM * FDIM) Ws[tid] = W[tid];
  if (tid < FDIM) { asv[tid] = a_s[tid]; adv[tid] = a_d[tid]; }
  __syncthreads();
  int n = blockIdx.x * blockDim.x + tid;
  if (n >= n_nodes) return;
  float xin[FDIM];
#pragma unroll
  for (int j = 0; j < FDIM; ++j) xin[j] = in[n * ld_in + j];
  float sa = 0.f, da = 0.f;
  half_t hrow[FPAD];
#pragma unroll
  for (int o = 0; o < FDIM; ++o) {
    float acc = 0.f;
#pragma unroll
    for (int k = 0; k < FDIM; ++k) acc += xin[k] * Ws[k * FDIM + o];
    hrow[o] = (half_t)acc;
    sa += acc * asv[o];
    da += acc * adv[o];
  }
  hrow[FDIM] = (half_t)sa;
  ad_[n] = da;
  float4 w0, w1;
  __builtin_memcpy(&w0, &hrow[0], 16);
  __builtin_memcpy(&w1, &hrow[8], 16);
  float4* dst = (float4*)(hp + (size_t)n * FPAD);
  dst[0] = w0;
  dst[1] = w1;
}

// ---- annotation-MLP stage rider: 8-way explicit ILP (R16 lesson: rider
// block lifetime = displacement window; R11 lesson: only explicit scalar
// loads produce loads-in-flight on this compiler) ----
__device__ __forceinline__ void mlp_rider(int g, int tid, int nthreads,
                                          const float* __restrict__ mIn,
                                          const float* __restrict__ mW,
                                          const float* __restrict__ mB,
                                          float* __restrict__ mOut,
                                          int Nout, int mAct,
                                          float* mins) {
  for (int k = tid; k < 300; k += nthreads) mins[k] = mIn[(size_t)g * 300 + k];
  __syncthreads();
  int j1 = tid;
  int j2 = tid + nthreads;
  bool p1 = (j1 < Nout), p2 = (j2 < Nout);
  if (!p1) return;
  float a0 = 0.f, a1 = 0.f, a2 = 0.f, a3 = 0.f;
  float a4 = 0.f, a5 = 0.f, a6 = 0.f, a7 = 0.f;
  float b0 = 0.f, b1 = 0.f, b2 = 0.f, b3 = 0.f;
  float b4 = 0.f, b5 = 0.f, b6 = 0.f, b7 = 0.f;
  int k = 0;
  for (; k + 7 < 300; k += 8) {
    float i0 = mins[k],     i1 = mins[k + 1], i2 = mins[k + 2], i3 = mins[k + 3];
    float i4 = mins[k + 4], i5 = mins[k + 5], i6 = mins[k + 6], i7 = mins[k + 7];
    float w0 = mW[k * Nout + j1];
    float w1 = mW[(k + 1) * Nout + j1];
    float w2 = mW[(k + 2) * Nout + j1];
    float w3 = mW[(k + 3) * Nout + j1];
    float w4 = mW[(k + 4) * Nout + j1];
    float w5 = mW[(k + 5) * Nout + j1];
    float w6 = mW[(k + 6) * Nout + j1];
    float w7 = mW[(k + 7) * Nout + j1];
    a0 += i0 * w0; a1 += i1 * w1; a2 += i2 * w2; a3 += i3 * w3;
    a4 += i4 * w4; a5 += i5 * w5; a6 += i6 * w6; a7 += i7 * w7;
    if (p2) {
      float v0 = mW[k * Nout + j2];
      float v1 = mW[(k + 1) * Nout + j2];
      float v2 = mW[(k + 2) * Nout + j2];
      float v3 = mW[(k + 3) * Nout + j2];
      float v4 = mW[(k + 4) * Nout + j2];
      float v5 = mW[(k + 5) * Nout + j2];
      float v6 = mW[(k + 6) * Nout + j2];
      float v7 = mW[(k + 7) * Nout + j2];
      b0 += i0 * v0; b1 += i1 * v1; b2 += i2 * v2; b3 += i3 * v3;
      b4 += i4 * v4; b5 += i5 * v5; b6 += i6 * v6; b7 += i7 * v7;
    }
  }
  for (; k < 300; ++k) {
    float ik = mins[k];
    a0 += ik * mW[k * Nout + j1];
    if (p2) b0 += ik * mW[k * Nout + j2];
  }
  float r1 = mB[j1] + ((a0 + a1) + (a2 + a3)) + ((a4 + a5) + (a6 + a7));
  if (mAct == 1) r1 = fmaxf(r1, 0.f);
  else if (mAct == 2) r1 = 1.f / (1.f + expf(-r1));
  mOut[(size_t)g * Nout + j1] = r1;
  if (p2) {
    float r2 = mB[j2] + ((b0 + b1) + (b2 + b3)) + ((b4 + b5) + (b6 + b7));
    if (mAct == 1) r2 = fmaxf(r2, 0.f);
    else if (mAct == 2) r2 = 1.f / (1.f + expf(-r2));
    mOut[(size_t)g * Nout + j2] = r2;
  }
}

// ---- fused GAT aggregate + FFN (+ next-layer transform) + MLP rider ----
// R8 main loop (best measured, 3x confirmed local optimum).
__global__ void k_gat(const int* __restrict__ rowptr, const int* __restrict__ csrB,
                      const half_t* __restrict__ hp, const float* __restrict__ ad_,
                      const float* __restrict__ cb, const float* __restrict__ fW,
                      const float* __restrict__ fb,
                      const float* __restrict__ nW, const float* __restrict__ nas,
                      const float* __restrict__ nad,
                      half_t* __restrict__ hp2, float* __restrict__ ad2,
                      float* __restrict__ fout,
                      const float* __restrict__ mIn, const float* __restrict__ mW,
                      const float* __restrict__ mB, float* __restrict__ mOut,
                      int mNout, int mAct, int mlpG,
                      int n_nodes, int do_relu, int fuse) {
  __shared__ float Ws[FDIM * FDIM];
  __shared__ float W2s[FDIM * FDIM];
  __shared__ float cbv[FDIM], fbv[FDIM], as2v[FDIM], ad2v[FDIM];
  __shared__ float aggT[16][16];
  __shared__ float outT[16][16];
  __shared__ float mins[304];
  int tid = threadIdx.x;

  if ((int)blockIdx.x < mlpG) {
    mlp_rider(blockIdx.x, tid, blockDim.x, mIn, mW, mB, mOut, mNout, mAct, mins);
    return;
  }

  if (tid < FDIM * FDIM) Ws[tid] = fW[tid];
  if (tid < FDIM) { cbv[tid] = cb[tid]; fbv[tid] = fb[tid]; }
  if (fuse) {
    if (tid < FDIM * FDIM) W2s[tid] = nW[tid];
    if (tid < FDIM) { as2v[tid] = nas[tid]; ad2v[tid] = nad[tid]; }
  }
  __syncthreads();
  int dl = tid >> 4;          // local dst 0..15
  int f  = tid & 15;          // feature lane 0..15 (slot 15 carries `as`)
  int d  = ((int)blockIdx.x - mlpG) * 16 + dl;
  float val = 0.f;
  if (d < n_nodes) {
    int rs = rowptr[d], re = rowptr[d + 1];
    float adv = ad_[d];
    const char* hb = (const char*)hp;
    int fo = f << 1;
    float den0 = 0.f, acc0 = 0.f, den1 = 0.f, acc1 = 0.f;
    int j = rs;
    for (; j + 7 < re; j += 8) {
      int o0 = csrB[j],     o1 = csrB[j + 1], o2 = csrB[j + 2], o3 = csrB[j + 3];
      int o4 = csrB[j + 4], o5 = csrB[j + 5], o6 = csrB[j + 6], o7 = csrB[j + 7];
      float hv0 = (float)*(const half_t*)(hb + o0 + fo);
      float hv1 = (float)*(const half_t*)(hb + o1 + fo);
      float hv2 = (float)*(const half_t*)(hb + o2 + fo);
      float hv3 = (float)*(const half_t*)(hb + o3 + fo);
      float hv4 = (float)*(const half_t*)(hb + o4 + fo);
      float hv5 = (float)*(const half_t*)(hb + o5 + fo);
      float hv6 = (float)*(const half_t*)(hb + o6 + fo);
      float hv7 = (float)*(const half_t*)(hb + o7 + fo);
      float w0 = __expf(leaky(__shfl(hv0, 15, 16) + adv));
      float w1 = __expf(leaky(__shfl(hv1, 15, 16) + adv));
      float w2 = __expf(leaky(__shfl(hv2, 15, 16) + adv));
      float w3 = __expf(leaky(__shfl(hv3, 15, 16) + adv));
      float w4 = __expf(leaky(__shfl(hv4, 15, 16) + adv));
      float w5 = __expf(leaky(__shfl(hv5, 15, 16) + adv));
      float w6 = __expf(leaky(__shfl(hv6, 15, 16) + adv));
      float w7 = __expf(leaky(__shfl(hv7, 15, 16) + adv));
      den0 += w0; acc0 += hv0 * w0;
      den1 += w1; acc1 += hv1 * w1;
      den0 += w2; acc0 += hv2 * w2;
      den1 += w3; acc1 += hv3 * w3;
      den0 += w4; acc0 += hv4 * w4;
      den1 += w5; acc1 += hv5 * w5;
      den0 += w6; acc0 += hv6 * w6;
      den1 += w7; acc1 += hv7 * w7;
    }
    for (; j < re; ++j) {
      int o0 = csrB[j];
      float hv0 = (float)*(const half_t*)(hb + o0 + fo);
      float w0 = __expf(leaky(__shfl(hv0, 15, 16) + adv));
      den0 += w0; acc0 += hv0 * w0;
    }
    val = (acc0 + acc1) / (den0 + den1 + 1e-16f);
  }
  aggT[dl][f] = (f < FDIM) ? (val + cbv[f]) : 0.f;
  __syncthreads();
  int o = f;
  float ffn = 0.f;
  if (o < FDIM) {
    ffn = fbv[o];
#pragma unroll
    for (int k = 0; k < FDIM; ++k) ffn += aggT[dl][k] * Ws[k * FDIM + o];
    if (do_relu) ffn = fmaxf(ffn, 0.f);
  }
  if (!fuse) {
    if (d < n_nodes) fout[d * FPAD + o] = (o < FDIM) ? ffn : 0.f;
    return;
  }
  // ---- fused next-layer transform: h2 = out @ nW ; sa2/da2 reductions ----
  outT[dl][o] = ffn;   // o==15 lane wrote ffn=0
  __syncthreads();
  if (d < n_nodes) {
    float h2 = 0.f;
    if (o < FDIM) {
#pragma unroll
      for (int k = 0; k < FDIM; ++k) h2 += outT[dl][k] * W2s[k * FDIM + o];
    }
    float pa = (o < FDIM) ? h2 * as2v[o] : 0.f;
    float pd = (o < FDIM) ? h2 * ad2v[o] : 0.f;
#pragma unroll
    for (int k = 8; k; k >>= 1) {
      pa += __shfl_xor(pa, k, 16);
      pd += __shfl_xor(pd, k, 16);
    }
    hp2[(size_t)d * FPAD + o] = (half_t)((o < FDIM) ? h2 : pa);
    if (o == 0) ad2[d] = pd;
  }
}

// ---- pooling + s4 rider (xann = sigmoidActs @ aW4 + ab4) ----
__device__ __forceinline__ int lowerb(const int* __restrict__ a, int n, int key) {
  int lo = 0, hi = n;
  while (lo < hi) { int mid = (lo + hi) >> 1; if (a[mid] < key) lo = mid + 1; else hi = mid; }
  return lo;
}

__global__ void k_pool(const float* __restrict__ fout, const int* __restrict__ batch,
                       float* __restrict__ pooled,
                       const float* __restrict__ acts,
                       const float* __restrict__ aW4, const float* __restrict__ ab4,
                       float* __restrict__ xann,
                       int n_nodes, int Gn) {
  __shared__ float ss[256], sm[256];
  __shared__ float mins[304];
  int tid = threadIdx.x;
  if ((int)blockIdx.x < Gn) {
    mlp_rider(blockIdx.x, tid, blockDim.x, acts, aW4, ab4, xann, 45, 0, mins);
    return;
  }
  int g = blockIdx.x - Gn;
  int s = lowerb(batch, n_nodes, g);
  int e = lowerb(batch, n_nodes, g + 1);
  int f = tid & 15;
  float sum = 0.f, mx = -INFINITY;
  for (int n = s + (tid >> 4); n < e; n += 16) {
    float v = fout[n * FPAD + f];
    sum += v;
    mx = fmaxf(mx, v);
  }
  ss[tid] = sum; sm[tid] = mx;
  __syncthreads();
  for (int step = 128; step >= 16; step >>= 1) {
    if (tid < step) { ss[tid] += ss[tid + step]; sm[tid] = fmaxf(sm[tid], sm[tid + step]); }
    __syncthreads();
  }
  if (tid < FDIM) {
    float cnt = (float)(e - s);
    float sv = ss[tid];
    pooled[g * 45 + tid] = sv;
    pooled[g * 45 + 15 + tid] = sm[tid];
    pooled[g * 45 + 30 + tid] = sv / fmaxf(cnt, 1.f);
  }
}

// ---- head: z=[pooled,xann] -> relu(z@m1W+m1b) -> sigmoid(@m2W+m2b) ----
__global__ void k_final(const float* __restrict__ pooled, const float* __restrict__ xann,
                        const float* __restrict__ m1W, const float* __restrict__ m1b,
                        const float* __restrict__ m2W, const float* __restrict__ m2b,
                        float* __restrict__ out) {
  __shared__ float z[90];
  __shared__ float z2[90];
  __shared__ float ps[128];
  int g = blockIdx.x;
  int t = threadIdx.x;  // 128
  if (t < 45) z[t] = pooled[g * 45 + t];
  else if (t < 90) z[t] = xann[g * 45 + (t - 45)];
  __syncthreads();
  if (t < 90) {
    float a0 = 0.f, a1 = 0.f;
    for (int k = 0; k < 90; k += 2) {
      float w0 = m1W[k * 90 + t];
      float w1 = m1W[(k + 1) * 90 + t];
      a0 += z[k] * w0; a1 += z[k + 1] * w1;
    }
    z2[t] = fmaxf(m1b[t] + a0 + a1, 0.f);
  }
  __syncthreads();
  if (t < 90) ps[t] = z2[t] * m2W[t];
  else ps[t] = 0.f;
  __syncthreads();
  if (t < 64) {
    float v = ps[t] + ps[t + 64];
#pragma unroll
    for (int k2 = 32; k2; k2 >>= 1) v += __shfl_xor(v, k2, 64);
    if (t == 0) out[g] = 1.f / (1.f + expf(-(v + m2b[0])));
  }
}

extern "C" void kernel_launch(void* const* d_in, const int* in_sizes, int n_in,
                              void* d_out, int out_size, void* d_ws, size_t ws_size,
                              hipStream_t stream) {
  const float* x   = (const float*)d_in[0];
  const int* ei    = (const int*)d_in[1];
  const int* batch = (const int*)d_in[2];
  const float* xA  = (const float*)d_in[3];

  const int N = in_sizes[0] / FDIM;
  const int E = in_sizes[1] / 2;
  const int G = in_sizes[3] / 300;
  const int ET = E + N;
  const int NB = (N + BWID - 1) >> BSH;   // dst buckets (<=512 for N<=131072)

  const int* srcI = ei;
  const int* dstI = ei + E;

  // ---- workspace layout (4-byte words) ----
  float* ws = (float*)d_ws;
  size_t layerW = (size_t)34 * N;  // hpA(8N)+hpB(8N)+adA(N)+adB(N)+fout(16N)
  size_t uSize = layerW > (size_t)ET ? layerW : (size_t)ET;
  size_t off = 0;
  int*    bbuf = (int*)(ws + off);
  half_t* hpA  = (half_t*)(ws + off);
  half_t* hpB  = (half_t*)(ws + off + (size_t)8 * N);
  float*  adA  = ws + off + (size_t)16 * N;
  float*  adB  = ws + off + (size_t)17 * N;
  float*  fout = ws + off + (size_t)18 * N;
  off += uSize;
  int*   rowptr = (int*)(ws + off); off += N + 1;
  int*   csr    = (int*)(ws + off); off += (size_t)ET;
  int*   bcnt   = (int*)(ws + off); off += 516;
  int*   boff   = (int*)(ws + off); off += 516;
  int*   bcur   = (int*)(ws + off); off += 516;
  float* pooled = ws + off; off += (size_t)G * 45;
  float* a1     = ws + off; off += (size_t)G * 300;
  float* a2     = ws + off; off += (size_t)G * 300;
  float* xann   = ws + off; off += (size_t)G * 45;

  const int B = 256;
  const int gN = (N + B - 1) / B;

  // ---- bucketed CSR build (R15 two-pass: 43us proven; R16 single-pass lost) --
  k_zero<<<(NB + B - 1) / B, B, 0, stream>>>(bcnt, NB);
  k_bhist<<<HB_GRID, HB_BLK, 0, stream>>>(dstI, bcnt, ET, E, NB);
  k_bscan<<<1, 512, 0, stream>>>(bcnt, boff, bcur, rowptr, NB, N, ET);
  k_bpart<<<HB_GRID, HB_BLK, 0, stream>>>(srcI, dstI, bcur, bbuf, ET, E, NB);
  k_bbuild<<<NB, 512, 0, stream>>>(boff, bbuf, rowptr, csr, N);

  // ---- weights ----
  const float* cW1  = (const float*)d_in[4];
  const float* cas1 = (const float*)d_in[5];
  const float* cad1 = (const float*)d_in[6];
  const float* cb1  = (const float*)d_in[7];
  const float* fW1  = (const float*)d_in[8];
  const float* fb1  = (const float*)d_in[9];
  const float* cW2  = (const float*)d_in[10];
  const float* cas2 = (const float*)d_in[11];
  const float* cad2 = (const float*)d_in[12];
  const float* cb2  = (const float*)d_in[13];
  const float* fW2  = (const float*)d_in[14];
  const float* fb2  = (const float*)d_in[15];
  const float* cW3  = (const float*)d_in[16];
  const float* cas3 = (const float*)d_in[17];
  const float* cad3 = (const float*)d_in[18];
  const float* cb3  = (const float*)d_in[19];
  const float* fW3  = (const float*)d_in[20];
  const float* fb3  = (const float*)d_in[21];
  const float* m1W  = (const float*)d_in[22];
  const float* m1b  = (const float*)d_in[23];
  const float* aW1  = (const float*)d_in[24];
  const float* ab1  = (const float*)d_in[25];
  const float* aW2  = (const float*)d_in[26];
  const float* ab2  = (const float*)d_in[27];
  const float* aW3  = (const float*)d_in[28];
  const float* ab3  = (const float*)d_in[29];
  const float* aW4  = (const float*)d_in[30];
  const float* ab4  = (const float*)d_in[31];
  const float* m2W  = (const float*)d_in[32];
  const float* m2b  = (const float*)d_in[33];

  // ---- 3 GAT layers, each carrying one annotation-MLP stage (R15 placement) --
  const int gGat = (N + 15) / 16;
  k_transform<<<gN, B, 0, stream>>>(x, FDIM, cW1, cas1, cad1, hpA, adA, N);
  k_gat<<<gGat + G, B, 0, stream>>>(rowptr, csr, hpA, adA, cb1, fW1, fb1,
                                    cW2, cas2, cad2, hpB, adB, nullptr,
                                    xA, aW1, ab1, a1, 300, 1, G,
                                    N, 1, 1);
  k_gat<<<gGat + G, B, 0, stream>>>(rowptr, csr, hpB, adB, cb2, fW2, fb2,
                                    cW3, cas3, cad3, hpA, adA, nullptr,
                                    a1, aW2, ab2, a2, 300, 1, G,
                                    N, 1, 1);
  k_gat<<<gGat + G, B, 0, stream>>>(rowptr, csr, hpA, adA, cb3, fW3, fb3,
                                    nullptr, nullptr, nullptr, nullptr, nullptr, fout,
                                    a2, aW3, ab3, a1, 300, 2, G,
                                    N, 0, 0);

  // ---- pooling + s4 rider ----
  k_pool<<<2 * G, B, 0, stream>>>(fout, batch, pooled, a1, aW4, ab4, xann, N, G);

  // ---- head ----
  k_final<<<G, 128, 0, stream>>>(pooled, xann, m1W, m1b, m2W, m2b, (float*)d_out);
}